// Round 8
// baseline (133.351 us; speedup 1.0000x reference)
//
#include <hip/hip_runtime.h>
#include <hip/hip_bf16.h>
#include <stdint.h>

#define NROWS 8192
#define DIM 512

typedef short bf16x8 __attribute__((ext_vector_type(8)));
typedef float f32x4 __attribute__((ext_vector_type(4)));

__device__ __forceinline__ unsigned short f2bf(float f) {
    union { float f; uint32_t u; } c; c.f = f;
    uint32_t u = c.u;
    return (unsigned short)((u + 0x7FFFu + ((u >> 16) & 1u)) >> 16);
}

__device__ __forceinline__ void gload16(const unsigned short* g, unsigned short* l) {
    __builtin_amdgcn_global_load_lds((const __attribute__((address_space(1))) void*)g,
                                     (__attribute__((address_space(3))) void*)l,
                                     16, 0, 0);
}

// ---------------- Kernel 1: L2-normalize rows -> bf16; also zero pos/neg ----------------
__global__ __launch_bounds__(256) void knorm(const float* __restrict__ in,
                                             unsigned short* __restrict__ out,
                                             float* __restrict__ pos,
                                             float* __restrict__ neg) {
    const int row  = (blockIdx.x << 2) + (threadIdx.x >> 6);
    const int lane = threadIdx.x & 63;
    if (threadIdx.x < 4)      pos[(blockIdx.x << 2) + threadIdx.x] = 0.0f;
    else if (threadIdx.x < 8) neg[(blockIdx.x << 2) + threadIdx.x - 4] = 0.0f;

    const float4* src = (const float4*)(in + (size_t)row * DIM);
    float4 a = src[lane];
    float4 b = src[lane + 64];
    float ss = a.x*a.x + a.y*a.y + a.z*a.z + a.w*a.w
             + b.x*b.x + b.y*b.y + b.z*b.z + b.w*b.w;
    #pragma unroll
    for (int m = 1; m < 64; m <<= 1) ss += __shfl_xor(ss, m);
    const float inv = 1.0f / sqrtf(ss);
    ushort4* dst = (ushort4*)(out + (size_t)row * DIM);
    ushort4 o;
    o.x = f2bf(a.x*inv); o.y = f2bf(a.y*inv); o.z = f2bf(a.z*inv); o.w = f2bf(a.w*inv);
    dst[lane] = o;
    o.x = f2bf(b.x*inv); o.y = f2bf(b.y*inv); o.z = f2bf(b.z*inv); o.w = f2bf(b.w*inv);
    dst[lane + 64] = o;
}

// ---------------- Kernel 2 (D0 = exact R5 best): upper-triangle fused GEMM ----------------
__global__ __launch_bounds__(1024, 1) void kgemm(const unsigned short* __restrict__ E,
                                                 float* __restrict__ pos,
                                                 float* __restrict__ neg) {
    __shared__ unsigned short lds[2][2][256 * 32];

    const int tid = threadIdx.x;
    const int w = tid >> 6;
    const int l = tid & 63;

    int rem = (int)((blockIdx.x & 7) * 66 + (blockIdx.x >> 3));
    int SI = -1, SJ = -1;
    #pragma unroll
    for (int s = 0; s < 10; s++) {
        constexpr int si_t[10] = {0,0,0,0,1,1,1,2,2,3};
        constexpr int sj_t[10] = {0,1,2,3,1,2,3,2,3,3};
        const int sz = (si_t[s] == sj_t[s]) ? 36 : 64;
        if (SI < 0) {
            if (rem < sz) { SI = si_t[s]; SJ = sj_t[s]; }
            else rem -= sz;
        }
    }
    int bi, bj;
    if (SI == SJ) {
        int x = 0;
        while (rem >= 8 - x) { rem -= 8 - x; x++; }
        bi = (SI << 3) + x; bj = (SI << 3) + x + rem;
    } else {
        bi = (SI << 3) + (rem >> 3);
        bj = (SJ << 3) + (rem & 7);
    }

    const int brow = bi << 8;
    const int bcol = bj << 8;
    const int wr = (w >> 2) << 6;
    const int wc = (w & 3) << 6;

    f32x4 acc[4][4];
    #pragma unroll
    for (int i = 0; i < 4; i++)
        #pragma unroll
        for (int j = 0; j < 4; j++) acc[i][j] = (f32x4)0.0f;

    const int g_src = (l & 3) ^ ((l >> 3) & 3);
    const int r_st  = (w << 4) + (l >> 2);

    auto STAGE = [&](int buf, int kt) {
        const size_t colb = (size_t)((kt << 5) + (g_src << 3));
        gload16(E + (size_t)(brow + r_st) * DIM + colb, &lds[buf][0][w << 9]);
        gload16(E + (size_t)(bcol + r_st) * DIM + colb, &lds[buf][1][w << 9]);
    };

    const int sgk = (((l >> 4) ^ ((l >> 1) & 3)) << 3);

    auto COMPUTE = [&](int buf) {
        const unsigned short* sA = lds[buf][0];
        const unsigned short* sB = lds[buf][1];
        bf16x8 aF[4], bF[4];
        #pragma unroll
        for (int mi = 0; mi < 4; mi++) {
            const int rr = wr + (mi << 4) + (l & 15);
            aF[mi] = *(const bf16x8*)&sA[(rr << 5) + sgk];
        }
        #pragma unroll
        for (int ni = 0; ni < 4; ni++) {
            const int rr = wc + (ni << 4) + (l & 15);
            bF[ni] = *(const bf16x8*)&sB[(rr << 5) + sgk];
        }
        #pragma unroll
        for (int mi = 0; mi < 4; mi++)
            #pragma unroll
            for (int ni = 0; ni < 4; ni++)
                acc[mi][ni] = __builtin_amdgcn_mfma_f32_16x16x32_bf16(
                    aF[mi], bF[ni], acc[mi][ni], 0, 0, 0);
    };

    STAGE(0, 0);
    #pragma unroll
    for (int kt = 0; kt < 16; kt++) {
        if (kt > 0) __builtin_amdgcn_s_barrier();
        if (kt < 15) {
            STAGE((kt + 1) & 1, kt + 1);
            asm volatile("s_waitcnt vmcnt(2)" ::: "memory");
        } else {
            asm volatile("s_waitcnt vmcnt(0)" ::: "memory");
        }
        __builtin_amdgcn_sched_barrier(0);
        __builtin_amdgcn_s_barrier();
        COMPUTE(kt & 1);
    }

    if (bi == bj) {
        #pragma unroll
        for (int mi = 0; mi < 4; mi++) {
            #pragma unroll
            for (int r = 0; r < 4; r++) {
                const int gi = brow + wr + (mi << 4) + ((l >> 4) << 2) + r;
                float p = 0.0f, n = 0.0f;
                #pragma unroll
                for (int ni = 0; ni < 4; ni++) {
                    const int gj = bcol + wc + (ni << 4) + (l & 15);
                    const float e = __expf(fmaf(acc[mi][ni][r], 10.0f, -10.0f));
                    if (gi == gj) {
                    } else if ((gi >> 2) == (gj >> 2)) {
                        p += e;
                    } else {
                        n += e;
                    }
                }
                #pragma unroll
                for (int m = 1; m < 16; m <<= 1) {
                    n += __shfl_xor(n, m);
                    p += __shfl_xor(p, m);
                }
                if ((l & 15) == 0) {
                    atomicAdd(&neg[gi], n);
                    atomicAdd(&pos[gi], p);
                }
            }
        }
    } else {
        float c[4] = {0.0f, 0.0f, 0.0f, 0.0f};
        #pragma unroll
        for (int mi = 0; mi < 4; mi++) {
            #pragma unroll
            for (int r = 0; r < 4; r++) {
                const int gi = brow + wr + (mi << 4) + ((l >> 4) << 2) + r;
                float n = 0.0f;
                #pragma unroll
                for (int ni = 0; ni < 4; ni++) {
                    const float e = __expf(fmaf(acc[mi][ni][r], 10.0f, -10.0f));
                    n += e;
                    c[ni] += e;
                }
                #pragma unroll
                for (int m = 1; m < 16; m <<= 1) n += __shfl_xor(n, m);
                if ((l & 15) == 0) atomicAdd(&neg[gi], n);
            }
        }
        #pragma unroll
        for (int ni = 0; ni < 4; ni++) {
            c[ni] += __shfl_xor(c[ni], 16);
            c[ni] += __shfl_xor(c[ni], 32);
            if ((l >> 4) == 0) {
                const int gj = bcol + wc + (ni << 4) + (l & 15);
                atomicAdd(&neg[gj], c[ni]);
            }
        }
    }
}

// ---------------- Ablation kernels (diagnostic only; results sunk via asm) ----------------
// V=1: full main loop, NO epilogue.      V=2: NO staging (ds_read+MFMA+barriers).
// V=3: staging+barriers only.            V=4: MFMA+barriers only.
// 256 blocks = 1 per CU, no tail: per-dispatch dur_us == T_block(variant).
template <int V>
__global__ __launch_bounds__(1024, 1) void kabl(const unsigned short* __restrict__ E) {
    __shared__ unsigned short lds[2][2][256 * 32];

    const int tid = threadIdx.x;
    const int w = tid >> 6;
    const int l = tid & 63;
    const int b = blockIdx.x;
    const int bi = b & 31;
    const int bj = bi ^ ((b >> 5) & 7);

    const int brow = bi << 8;
    const int bcol = bj << 8;
    const int wr = (w >> 2) << 6;
    const int wc = (w & 3) << 6;

    f32x4 acc[4][4];
    #pragma unroll
    for (int i = 0; i < 4; i++)
        #pragma unroll
        for (int j = 0; j < 4; j++) acc[i][j] = (f32x4)0.0f;

    const int g_src = (l & 3) ^ ((l >> 3) & 3);
    const int r_st  = (w << 4) + (l >> 2);

    auto STAGE = [&](int buf, int kt) {
        const size_t colb = (size_t)((kt << 5) + (g_src << 3));
        gload16(E + (size_t)(brow + r_st) * DIM + colb, &lds[buf][0][w << 9]);
        gload16(E + (size_t)(bcol + r_st) * DIM + colb, &lds[buf][1][w << 9]);
    };

    const int sgk = (((l >> 4) ^ ((l >> 1) & 3)) << 3);

    auto COMPUTE = [&](int buf) {
        const unsigned short* sA = lds[buf][0];
        const unsigned short* sB = lds[buf][1];
        bf16x8 aF[4], bF[4];
        #pragma unroll
        for (int mi = 0; mi < 4; mi++) {
            const int rr = wr + (mi << 4) + (l & 15);
            aF[mi] = *(const bf16x8*)&sA[(rr << 5) + sgk];
        }
        #pragma unroll
        for (int ni = 0; ni < 4; ni++) {
            const int rr = wc + (ni << 4) + (l & 15);
            bF[ni] = *(const bf16x8*)&sB[(rr << 5) + sgk];
        }
        #pragma unroll
        for (int mi = 0; mi < 4; mi++)
            #pragma unroll
            for (int ni = 0; ni < 4; ni++)
                acc[mi][ni] = __builtin_amdgcn_mfma_f32_16x16x32_bf16(
                    aF[mi], bF[ni], acc[mi][ni], 0, 0, 0);
    };

    if constexpr (V == 1) {                    // main loop, no epilogue
        STAGE(0, 0);
        #pragma unroll
        for (int kt = 0; kt < 16; kt++) {
            if (kt > 0) __builtin_amdgcn_s_barrier();
            if (kt < 15) {
                STAGE((kt + 1) & 1, kt + 1);
                asm volatile("s_waitcnt vmcnt(2)" ::: "memory");
            } else {
                asm volatile("s_waitcnt vmcnt(0)" ::: "memory");
            }
            __builtin_amdgcn_sched_barrier(0);
            __builtin_amdgcn_s_barrier();
            COMPUTE(kt & 1);
        }
    } else if constexpr (V == 2) {             // no staging: ds_read+MFMA+barriers
        STAGE(0, 0);
        asm volatile("s_waitcnt vmcnt(0)" ::: "memory");
        #pragma unroll
        for (int kt = 0; kt < 16; kt++) {
            if (kt > 0) __builtin_amdgcn_s_barrier();
            __builtin_amdgcn_sched_barrier(0);
            __builtin_amdgcn_s_barrier();
            COMPUTE(kt & 1);
        }
    } else if constexpr (V == 3) {             // staging+barriers only
        STAGE(0, 0);
        #pragma unroll
        for (int kt = 0; kt < 16; kt++) {
            if (kt > 0) __builtin_amdgcn_s_barrier();
            if (kt < 15) {
                STAGE((kt + 1) & 1, kt + 1);
                asm volatile("s_waitcnt vmcnt(2)" ::: "memory");
            } else {
                asm volatile("s_waitcnt vmcnt(0)" ::: "memory");
            }
            __builtin_amdgcn_sched_barrier(0);
            __builtin_amdgcn_s_barrier();
        }
        unsigned int v = *(volatile unsigned int*)&lds[0][0][tid << 1];
        asm volatile("" :: "v"(v));
    } else {                                   // V==4: MFMA+barriers only
        bf16x8 aF[4], bF[4];
        #pragma unroll
        for (int mi = 0; mi < 4; mi++)
            #pragma unroll
            for (int q = 0; q < 8; q++) {
                aF[mi][q] = (short)(tid + q + mi);
                bF[mi][q] = (short)(tid - q - mi);
            }
        #pragma unroll
        for (int kt = 0; kt < 16; kt++) {
            if (kt > 0) __builtin_amdgcn_s_barrier();
            __builtin_amdgcn_sched_barrier(0);
            __builtin_amdgcn_s_barrier();
            #pragma unroll
            for (int mi = 0; mi < 4; mi++)
                #pragma unroll
                for (int ni = 0; ni < 4; ni++)
                    acc[mi][ni] = __builtin_amdgcn_mfma_f32_16x16x32_bf16(
                        aF[mi], bF[ni], acc[mi][ni], 0, 0, 0);
        }
    }

    // keep accumulators live without any memory write (rule #17)
    #pragma unroll
    for (int i = 0; i < 4; i++)
        #pragma unroll
        for (int j = 0; j < 4; j++)
            asm volatile("" :: "v"(acc[i][j][0]), "v"(acc[i][j][1]),
                               "v"(acc[i][j][2]), "v"(acc[i][j][3]));
}

// ---------------- Kernel 3: final loss reduction ----------------
__global__ __launch_bounds__(1024) void kloss(const float* __restrict__ pos,
                                              const float* __restrict__ neg,
                                              float* __restrict__ out) {
    const int tid = threadIdx.x;
    float s = 0.0f;
    for (int i = tid; i < NROWS; i += 1024) {
        const float p = pos[i];
        const float n = neg[i];
        s += __logf(p + n + 1e-8f) - __logf(p);
    }
    #pragma unroll
    for (int m = 1; m < 64; m <<= 1) s += __shfl_xor(s, m);
    __shared__ float red[16];
    if ((tid & 63) == 0) red[tid >> 6] = s;
    __syncthreads();
    if (tid == 0) {
        float t = 0.0f;
        #pragma unroll
        for (int i = 0; i < 16; i++) t += red[i];
        out[0] = t / (float)NROWS;
    }
}

extern "C" void kernel_launch(void* const* d_in, const int* in_sizes, int n_in,
                              void* d_out, int out_size, void* d_ws, size_t ws_size,
                              hipStream_t stream) {
    (void)in_sizes; (void)n_in; (void)out_size; (void)ws_size;
    const float* emb = (const float*)d_in[0];
    unsigned short* En = (unsigned short*)d_ws;                       // 8 MB bf16
    float* pos = (float*)((char*)d_ws + (size_t)NROWS * DIM * 2);     // 32 KB
    float* neg = pos + NROWS;                                         // 32 KB

    knorm<<<NROWS / 4, 256, 0, stream>>>(emb, En, pos, neg);
    kgemm<<<528, 1024, 0, stream>>>(En, pos, neg);
    kloss<<<1, 1024, 0, stream>>>(pos, neg, (float*)d_out);

    // ---- diagnostic ablations (deterministic, write nothing) ----
    kabl<1><<<256, 1024, 0, stream>>>(En);
    kabl<2><<<256, 1024, 0, stream>>>(En);
    kabl<3><<<256, 1024, 0, stream>>>(En);
    kabl<4><<<256, 1024, 0, stream>>>(En);
}

// Round 9
// 98.521 us; speedup vs baseline: 1.3535x; 1.3535x over previous
//
#include <hip/hip_runtime.h>
#include <hip/hip_bf16.h>
#include <stdint.h>

#define NROWS 8192
#define DIM 512

typedef short bf16x8 __attribute__((ext_vector_type(8)));
typedef float f32x4 __attribute__((ext_vector_type(4)));

__device__ __forceinline__ unsigned short f2bf(float f) {
    union { float f; uint32_t u; } c; c.f = f;
    uint32_t u = c.u;
    return (unsigned short)((u + 0x7FFFu + ((u >> 16) & 1u)) >> 16);
}

__device__ __forceinline__ void gload16(const unsigned short* g, unsigned short* l) {
    __builtin_amdgcn_global_load_lds((const __attribute__((address_space(1))) void*)g,
                                     (__attribute__((address_space(3))) void*)l,
                                     16, 0, 0);
}

// ---------------- Kernel 1: L2-normalize rows -> bf16; also zero pos/neg ----------------
__global__ __launch_bounds__(256) void knorm(const float* __restrict__ in,
                                             unsigned short* __restrict__ out,
                                             float* __restrict__ pos,
                                             float* __restrict__ neg) {
    const int row  = (blockIdx.x << 2) + (threadIdx.x >> 6);
    const int lane = threadIdx.x & 63;
    if (threadIdx.x < 4)      pos[(blockIdx.x << 2) + threadIdx.x] = 0.0f;
    else if (threadIdx.x < 8) neg[(blockIdx.x << 2) + threadIdx.x - 4] = 0.0f;

    const float4* src = (const float4*)(in + (size_t)row * DIM);
    float4 a = src[lane];
    float4 b = src[lane + 64];
    float ss = a.x*a.x + a.y*a.y + a.z*a.z + a.w*a.w
             + b.x*b.x + b.y*b.y + b.z*b.z + b.w*b.w;
    #pragma unroll
    for (int m = 1; m < 64; m <<= 1) ss += __shfl_xor(ss, m);
    const float inv = 1.0f / sqrtf(ss);
    ushort4* dst = (ushort4*)(out + (size_t)row * DIM);
    ushort4 o;
    o.x = f2bf(a.x*inv); o.y = f2bf(a.y*inv); o.z = f2bf(a.z*inv); o.w = f2bf(a.w*inv);
    dst[lane] = o;
    o.x = f2bf(b.x*inv); o.y = f2bf(b.y*inv); o.z = f2bf(b.z*inv); o.w = f2bf(b.w*inv);
    dst[lane + 64] = o;
}

// ---------------- Kernel 2: 8-phase-style 256x256 fused E*E^T (m201 port) ----------------
// 8 waves (2M x 4N), per-wave 128x64 output (acc[8][4]), BK=64, K=512 -> 8 K-tiles.
// LDS 128 KB: lds[2][4][128*64] = [buf][slot: 0=Alo 1=Ahi 2=Blo 3=Bhi].
// Per K-tile t (buf = t&1), 4 phases; each phase: stage ONE half-tile
// (2 gload16/thread) || ds_read next A mi-pair || 16 MFMA (setprio-wrapped),
// single s_barrier between phases. B-frags (8 x b128) are register-resident
// for the whole tile (read once at phase 0) -> B slots of buf free after p0,
// so B(t+2) stages into the SAME buf at p2/p3. A(t+1) -> buf^1 at p0/p1.
// Per-thread vmcnt ledger: ... t-1.p0:Alo(t) t-1.p1:Ahi(t) t-1.p2:Blo(t+1)
// t-1.p3:Bhi(t+1) t.p0:Alo(t+1) -> tile t needs through t-1.p1 => allowed
// outstanding = 3 stages x 2 loads = vmcnt(6), once per K-tile, never 0
// until the last tile. Swizzle: stored(r,g) = data(r, g^(r&7)); linear
// gload_lds dest + inverse-swizzled source + XOR'd ds_read (0 conflicts,
// verified R0/R1). Supertile XCD map (R2/R5-verified): 528 = 8 XCDs x 66.
__global__ __launch_bounds__(512, 2) void kgemm(const unsigned short* __restrict__ E,
                                                float* __restrict__ pos,
                                                float* __restrict__ neg) {
    __shared__ unsigned short lds[2][4][128 * 64];

    const int tid = threadIdx.x;
    const int w = tid >> 6;          // 0..7
    const int l = tid & 63;

    // ---- block id -> (bi, bj): supertile triangle decode ----
    int rem = (int)((blockIdx.x & 7) * 66 + (blockIdx.x >> 3));
    int SI = -1, SJ = -1;
    #pragma unroll
    for (int s = 0; s < 10; s++) {
        constexpr int si_t[10] = {0,0,0,0,1,1,1,2,2,3};
        constexpr int sj_t[10] = {0,1,2,3,1,2,3,2,3,3};
        const int sz = (si_t[s] == sj_t[s]) ? 36 : 64;
        if (SI < 0) {
            if (rem < sz) { SI = si_t[s]; SJ = sj_t[s]; }
            else rem -= sz;
        }
    }
    int bi, bj;
    if (SI == SJ) {
        int x = 0;
        while (rem >= 8 - x) { rem -= 8 - x; x++; }
        bi = (SI << 3) + x; bj = (SI << 3) + x + rem;
    } else {
        bi = (SI << 3) + (rem >> 3);
        bj = (SJ << 3) + (rem & 7);
    }

    const int brow = bi << 8;
    const int bcol = bj << 8;
    const int wrow = (w >> 2) << 7;      // 0 or 128
    const int wcol = (w & 3) << 6;       // 0,64,128,192

    f32x4 acc[8][4];
    #pragma unroll
    for (int i = 0; i < 8; i++)
        #pragma unroll
        for (int j = 0; j < 4; j++) acc[i][j] = (f32x4)0.0f;

    // staging geometry (linear LDS dest; inverse-swizzled global source)
    const int g_src = (l & 7) ^ (l >> 3);

    auto STAGE = [&](int buf, int slot, int rowbase, int kt) {
        #pragma unroll
        for (int q = 0; q < 2; q++) {
            const int row = (q << 6) + (tid >> 3);               // 0..127
            gload16(E + (size_t)(rowbase + row) * DIM + (kt << 6) + (g_src << 3),
                    &lds[buf][slot][((q << 6) + (w << 3)) << 6]);
        }
    };

    // ds_read geometry
    const int ar  = l & 15;                                  // row base within frag
    const int br0 = ((w & 1) << 6) + (l & 15);               // B local row base
    const int sg0 = (((0 << 2) + (l >> 4)) ^ (l & 7)) << 3;  // kk=0 swizzled group off
    const int sg1 = (((1 << 2) + (l >> 4)) ^ (l & 7)) << 3;  // kk=1
    const int as  = w >> 2;                                  // A slot (0=lo,1=hi)
    const int bs  = 2 + ((w >> 1) & 1);                      // B slot (2=lo,3=hi)

    bf16x8 bF[8], aA[4], aB[4];

#define READ_A(AF, M0, S)                                                    \
    AF[0] = *(const bf16x8*)&S[((((M0)    ) << 4) + ar) * 64 + sg0];         \
    AF[1] = *(const bf16x8*)&S[((((M0)    ) << 4) + ar) * 64 + sg1];         \
    AF[2] = *(const bf16x8*)&S[((((M0) + 1) << 4) + ar) * 64 + sg0];         \
    AF[3] = *(const bf16x8*)&S[((((M0) + 1) << 4) + ar) * 64 + sg1];

#define READ_B(S)                                                            \
    _Pragma("unroll")                                                        \
    for (int ni = 0; ni < 4; ni++) {                                         \
        bF[ni*2+0] = *(const bf16x8*)&S[(br0 + (ni << 4)) * 64 + sg0];       \
        bF[ni*2+1] = *(const bf16x8*)&S[(br0 + (ni << 4)) * 64 + sg1];       \
    }

#define MFMA_PH(AF, M0)                                                      \
    __builtin_amdgcn_s_setprio(1);                                           \
    _Pragma("unroll")                                                        \
    for (int ni = 0; ni < 4; ni++) {                                         \
        acc[(M0)+0][ni] = __builtin_amdgcn_mfma_f32_16x16x32_bf16(           \
            AF[0], bF[ni*2+0], acc[(M0)+0][ni], 0, 0, 0);                    \
        acc[(M0)+0][ni] = __builtin_amdgcn_mfma_f32_16x16x32_bf16(           \
            AF[1], bF[ni*2+1], acc[(M0)+0][ni], 0, 0, 0);                    \
        acc[(M0)+1][ni] = __builtin_amdgcn_mfma_f32_16x16x32_bf16(           \
            AF[2], bF[ni*2+0], acc[(M0)+1][ni], 0, 0, 0);                    \
        acc[(M0)+1][ni] = __builtin_amdgcn_mfma_f32_16x16x32_bf16(           \
            AF[3], bF[ni*2+1], acc[(M0)+1][ni], 0, 0, 0);                    \
    }                                                                        \
    __builtin_amdgcn_s_setprio(0);

    // ---- prologue: B(0), A(0), B(1) = 6 half-tiles, 12 loads/thread ----
    STAGE(0, 2, bcol,       0);
    STAGE(0, 3, bcol + 128, 0);
    STAGE(0, 0, brow,       0);
    STAGE(0, 1, brow + 128, 0);
    STAGE(1, 2, bcol,       1);
    STAGE(1, 3, bcol + 128, 1);

    #pragma unroll
    for (int t = 0; t < 8; t++) {
        const int buf = t & 1;
        const unsigned short* A = lds[buf][as];
        const unsigned short* B = lds[buf][bs];

        // ---- phase 0 ----
        if (t < 7) {
            STAGE(buf ^ 1, 0, brow, t + 1);                  // Alo(t+1)
            asm volatile("s_waitcnt vmcnt(6)" ::: "memory");
        } else {
            asm volatile("s_waitcnt vmcnt(0)" ::: "memory");
        }
        __builtin_amdgcn_sched_barrier(0);
        __builtin_amdgcn_s_barrier();                        // tile t data ready
        __builtin_amdgcn_sched_barrier(0);
        READ_B(B);
        READ_A(aA, 0, A);
        MFMA_PH(aA, 0);
        READ_A(aB, 2, A);
        __builtin_amdgcn_s_barrier();                        // B slots of buf free
        // ---- phase 1 ----
        if (t < 7) STAGE(buf ^ 1, 1, brow + 128, t + 1);     // Ahi(t+1)
        MFMA_PH(aB, 2);
        READ_A(aA, 4, A);
        __builtin_amdgcn_s_barrier();
        // ---- phase 2 ----
        if (t < 6) STAGE(buf, 2, bcol, t + 2);               // Blo(t+2) into freed slot
        MFMA_PH(aA, 4);
        READ_A(aB, 6, A);
        __builtin_amdgcn_s_barrier();
        // ---- phase 3 ----
        if (t < 6) STAGE(buf, 3, bcol + 128, t + 2);         // Bhi(t+2)
        MFMA_PH(aB, 6);
        __builtin_amdgcn_s_barrier();
    }

    // ---- epilogue: exp(10*dot - 10), classify/scatter, reduce, atomics ----
    if (bi == bj) {
        #pragma unroll
        for (int mi = 0; mi < 8; mi++) {
            #pragma unroll
            for (int r = 0; r < 4; r++) {
                const int gi = brow + wrow + (mi << 4) + ((l >> 4) << 2) + r;
                float p = 0.0f, n = 0.0f;
                #pragma unroll
                for (int ni = 0; ni < 4; ni++) {
                    const int gj = bcol + wcol + (ni << 4) + (l & 15);
                    const float e = __expf(fmaf(acc[mi][ni][r], 10.0f, -10.0f));
                    if (gi == gj) {
                    } else if ((gi >> 2) == (gj >> 2)) {
                        p += e;
                    } else {
                        n += e;
                    }
                }
                #pragma unroll
                for (int m = 1; m < 16; m <<= 1) {
                    n += __shfl_xor(n, m);
                    p += __shfl_xor(p, m);
                }
                if ((l & 15) == 0) {
                    atomicAdd(&neg[gi], n);
                    atomicAdd(&pos[gi], p);
                }
            }
        }
    } else {
        float c[4] = {0.0f, 0.0f, 0.0f, 0.0f};
        #pragma unroll
        for (int mi = 0; mi < 8; mi++) {
            #pragma unroll
            for (int r = 0; r < 4; r++) {
                const int gi = brow + wrow + (mi << 4) + ((l >> 4) << 2) + r;
                float n = 0.0f;
                #pragma unroll
                for (int ni = 0; ni < 4; ni++) {
                    const float e = __expf(fmaf(acc[mi][ni][r], 10.0f, -10.0f));
                    n += e;
                    c[ni] += e;
                }
                #pragma unroll
                for (int m = 1; m < 16; m <<= 1) n += __shfl_xor(n, m);
                if ((l & 15) == 0) atomicAdd(&neg[gi], n);
            }
        }
        #pragma unroll
        for (int ni = 0; ni < 4; ni++) {
            c[ni] += __shfl_xor(c[ni], 16);
            c[ni] += __shfl_xor(c[ni], 32);
            if ((l >> 4) == 0) {
                const int gj = bcol + wcol + (ni << 4) + (l & 15);
                atomicAdd(&neg[gj], c[ni]);
            }
        }
    }
#undef READ_A
#undef READ_B
#undef MFMA_PH
}

// ---------------- Kernel 3: final loss reduction ----------------
__global__ __launch_bounds__(1024) void kloss(const float* __restrict__ pos,
                                              const float* __restrict__ neg,
                                              float* __restrict__ out) {
    const int tid = threadIdx.x;
    float s = 0.0f;
    for (int i = tid; i < NROWS; i += 1024) {
        const float p = pos[i];
        const float n = neg[i];
        s += __logf(p + n + 1e-8f) - __logf(p);
    }
    #pragma unroll
    for (int m = 1; m < 64; m <<= 1) s += __shfl_xor(s, m);
    __shared__ float red[16];
    if ((tid & 63) == 0) red[tid >> 6] = s;
    __syncthreads();
    if (tid == 0) {
        float t = 0.0f;
        #pragma unroll
        for (int i = 0; i < 16; i++) t += red[i];
        out[0] = t / (float)NROWS;
    }
}

extern "C" void kernel_launch(void* const* d_in, const int* in_sizes, int n_in,
                              void* d_out, int out_size, void* d_ws, size_t ws_size,
                              hipStream_t stream) {
    (void)in_sizes; (void)n_in; (void)out_size; (void)ws_size;
    const float* emb = (const float*)d_in[0];
    unsigned short* En = (unsigned short*)d_ws;                       // 8 MB bf16
    float* pos = (float*)((char*)d_ws + (size_t)NROWS * DIM * 2);     // 32 KB
    float* neg = pos + NROWS;                                         // 32 KB

    knorm<<<NROWS / 4, 256, 0, stream>>>(emb, En, pos, neg);
    kgemm<<<528, 512, 0, stream>>>(En, pos, neg);
    kloss<<<1, 1024, 0, stream>>>(pos, neg, (float*)d_out);
}

// Round 10
// 80.936 us; speedup vs baseline: 1.6476x; 1.2173x over previous
//
#include <hip/hip_runtime.h>
#include <hip/hip_bf16.h>
#include <stdint.h>

#define NROWS 8192
#define DIM 512

typedef short bf16x8 __attribute__((ext_vector_type(8)));
typedef float f32x4 __attribute__((ext_vector_type(4)));

__device__ __forceinline__ unsigned short f2bf(float f) {
    union { float f; uint32_t u; } c; c.f = f;
    uint32_t u = c.u;
    return (unsigned short)((u + 0x7FFFu + ((u >> 16) & 1u)) >> 16);
}

__device__ __forceinline__ void gload16(const unsigned short* g, unsigned short* l) {
    __builtin_amdgcn_global_load_lds((const __attribute__((address_space(1))) void*)g,
                                     (__attribute__((address_space(3))) void*)l,
                                     16, 0, 0);
}

// ---------------- Kernel 1: L2-normalize rows -> bf16 ----------------
__global__ __launch_bounds__(256) void knorm(const float* __restrict__ in,
                                             unsigned short* __restrict__ out) {
    const int row  = (blockIdx.x << 2) + (threadIdx.x >> 6);
    const int lane = threadIdx.x & 63;
    const float4* src = (const float4*)(in + (size_t)row * DIM);
    float4 a = src[lane];
    float4 b = src[lane + 64];
    float ss = a.x*a.x + a.y*a.y + a.z*a.z + a.w*a.w
             + b.x*b.x + b.y*b.y + b.z*b.z + b.w*b.w;
    #pragma unroll
    for (int m = 1; m < 64; m <<= 1) ss += __shfl_xor(ss, m);
    const float inv = 1.0f / sqrtf(ss);
    ushort4* dst = (ushort4*)(out + (size_t)row * DIM);
    ushort4 o;
    o.x = f2bf(a.x*inv); o.y = f2bf(a.y*inv); o.z = f2bf(a.z*inv); o.w = f2bf(a.w*inv);
    dst[lane] = o;
    o.x = f2bf(b.x*inv); o.y = f2bf(b.y*inv); o.z = f2bf(b.z*inv); o.w = f2bf(b.w*inv);
    dst[lane + 64] = o;
}

// ---------------- Kernel 2: R5 main loop + ATOMIC-FREE partial-sum epilogue ----------------
// Main loop identical to R5 (best measured: 256x256 tile, 16 waves 4x4, BK=32,
// dbuf LDS, counted vmcnt(2), supertile XCD map, proven 0-conflict swizzle).
// Epilogue: NO global atomics. Per block: butterfly-reduce row/col/pos partials,
// assemble across waves in 12 KB of (reused) LDS, write one compact record:
//   part[lin][0][256] = row-sums, part[lin][1][256] = col-sums (off-diag only),
//   pospart[bi][256]  = positive sums (diag only).
// lin = the XCD-remapped linear block id (bijective 0..527); kred inverts it.
__global__ __launch_bounds__(1024, 1) void kgemm(const unsigned short* __restrict__ E,
                                                 float* __restrict__ part,
                                                 float* __restrict__ pospart) {
    __shared__ unsigned short lds[2][2][256 * 32];

    const int tid = threadIdx.x;
    const int w = tid >> 6;
    const int l = tid & 63;

    // ---- block id -> (bi, bj): supertile triangle decode ----
    const int lin = (int)((blockIdx.x & 7) * 66 + (blockIdx.x >> 3));
    int rem = lin;
    int SI = -1, SJ = -1;
    #pragma unroll
    for (int s = 0; s < 10; s++) {
        constexpr int si_t[10] = {0,0,0,0,1,1,1,2,2,3};
        constexpr int sj_t[10] = {0,1,2,3,1,2,3,2,3,3};
        const int sz = (si_t[s] == sj_t[s]) ? 36 : 64;
        if (SI < 0) {
            if (rem < sz) { SI = si_t[s]; SJ = sj_t[s]; }
            else rem -= sz;
        }
    }
    int bi, bj;
    if (SI == SJ) {
        int x = 0;
        while (rem >= 8 - x) { rem -= 8 - x; x++; }
        bi = (SI << 3) + x; bj = (SI << 3) + x + rem;
    } else {
        bi = (SI << 3) + (rem >> 3);
        bj = (SJ << 3) + (rem & 7);
    }

    const int brow = bi << 8;
    const int bcol = bj << 8;
    const int wr = (w >> 2) << 6;
    const int wc = (w & 3) << 6;

    f32x4 acc[4][4];
    #pragma unroll
    for (int i = 0; i < 4; i++)
        #pragma unroll
        for (int j = 0; j < 4; j++) acc[i][j] = (f32x4)0.0f;

    const int g_src = (l & 3) ^ ((l >> 3) & 3);
    const int r_st  = (w << 4) + (l >> 2);

    auto STAGE = [&](int buf, int kt) {
        const size_t colb = (size_t)((kt << 5) + (g_src << 3));
        gload16(E + (size_t)(brow + r_st) * DIM + colb, &lds[buf][0][w << 9]);
        gload16(E + (size_t)(bcol + r_st) * DIM + colb, &lds[buf][1][w << 9]);
    };

    const int sgk = (((l >> 4) ^ ((l >> 1) & 3)) << 3);

    auto COMPUTE = [&](int buf) {
        const unsigned short* sA = lds[buf][0];
        const unsigned short* sB = lds[buf][1];
        bf16x8 aF[4], bF[4];
        #pragma unroll
        for (int mi = 0; mi < 4; mi++) {
            const int rr = wr + (mi << 4) + (l & 15);
            aF[mi] = *(const bf16x8*)&sA[(rr << 5) + sgk];
        }
        #pragma unroll
        for (int ni = 0; ni < 4; ni++) {
            const int rr = wc + (ni << 4) + (l & 15);
            bF[ni] = *(const bf16x8*)&sB[(rr << 5) + sgk];
        }
        #pragma unroll
        for (int mi = 0; mi < 4; mi++)
            #pragma unroll
            for (int ni = 0; ni < 4; ni++)
                acc[mi][ni] = __builtin_amdgcn_mfma_f32_16x16x32_bf16(
                    aF[mi], bF[ni], acc[mi][ni], 0, 0, 0);
    };

    STAGE(0, 0);
    #pragma unroll
    for (int kt = 0; kt < 16; kt++) {
        if (kt > 0) __builtin_amdgcn_s_barrier();
        if (kt < 15) {
            STAGE((kt + 1) & 1, kt + 1);
            asm volatile("s_waitcnt vmcnt(2)" ::: "memory");
        } else {
            asm volatile("s_waitcnt vmcnt(0)" ::: "memory");
        }
        __builtin_amdgcn_sched_barrier(0);
        __builtin_amdgcn_s_barrier();
        COMPUTE(kt & 1);
    }

    // ---- epilogue: exp(10*dot - 10), classify, LDS assemble, streaming store ----
    float* lds_row = (float*)&lds[0][0][0];       // [4][256]
    float* lds_col = lds_row + 1024;              // [4][256]
    float* lds_pos = lds_row + 2048;              // [4][256]

    __syncthreads();   // all COMPUTE reads done before LDS reuse

    if (bi == bj) {
        #pragma unroll
        for (int mi = 0; mi < 4; mi++) {
            #pragma unroll
            for (int r = 0; r < 4; r++) {
                const int lrow = wr + (mi << 4) + ((l >> 4) << 2) + r;
                const int gi = brow + lrow;
                float p = 0.0f, n = 0.0f;
                #pragma unroll
                for (int ni = 0; ni < 4; ni++) {
                    const int gj = bcol + wc + (ni << 4) + (l & 15);
                    const float e = __expf(fmaf(acc[mi][ni][r], 10.0f, -10.0f));
                    if (gi == gj) {
                    } else if ((gi >> 2) == (gj >> 2)) {
                        p += e;
                    } else {
                        n += e;
                    }
                }
                #pragma unroll
                for (int m = 1; m < 16; m <<= 1) {
                    n += __shfl_xor(n, m);
                    p += __shfl_xor(p, m);
                }
                if ((l & 15) == 0) {
                    lds_row[((w & 3) << 8) + lrow] = n;
                    lds_pos[((w & 3) << 8) + lrow] = p;
                }
            }
        }
    } else {
        float c[4] = {0.0f, 0.0f, 0.0f, 0.0f};
        #pragma unroll
        for (int mi = 0; mi < 4; mi++) {
            #pragma unroll
            for (int r = 0; r < 4; r++) {
                const int lrow = wr + (mi << 4) + ((l >> 4) << 2) + r;
                float n = 0.0f;
                #pragma unroll
                for (int ni = 0; ni < 4; ni++) {
                    const float e = __expf(fmaf(acc[mi][ni][r], 10.0f, -10.0f));
                    n += e;
                    c[ni] += e;
                }
                #pragma unroll
                for (int m = 1; m < 16; m <<= 1) n += __shfl_xor(n, m);
                if ((l & 15) == 0) lds_row[((w & 3) << 8) + lrow] = n;
            }
        }
        #pragma unroll
        for (int ni = 0; ni < 4; ni++) {
            c[ni] += __shfl_xor(c[ni], 16);
            c[ni] += __shfl_xor(c[ni], 32);
            if ((l >> 4) == 0)
                lds_col[((w >> 2) << 8) + wc + (ni << 4) + l] = c[ni];
        }
    }
    __syncthreads();

    if (tid < 256) {
        const float s = lds_row[tid] + lds_row[256 + tid]
                      + lds_row[512 + tid] + lds_row[768 + tid];
        part[((size_t)lin << 9) + tid] = s;
    } else if (tid < 512) {
        if (bi != bj) {
            const int cc = tid - 256;
            const float s = lds_col[cc] + lds_col[256 + cc]
                          + lds_col[512 + cc] + lds_col[768 + cc];
            part[((size_t)lin << 9) + 256 + cc] = s;
        }
    } else if (tid < 768) {
        if (bi == bj) {
            const int rr = tid - 512;
            const float s = lds_pos[rr] + lds_pos[256 + rr]
                          + lds_pos[512 + rr] + lds_pos[768 + rr];
            pospart[(bi << 8) + rr] = s;
        }
    }
}

// ---------------- Kernel 3: gather partials, compute loss, reduce ----------------
// Block T (0..31) handles rows T*256..T*256+255. Row r needs:
//   rowparts of blocks (T,bj) bj=T..31, colparts of blocks (bi,T) bi=0..T-1,
//   pospart[T][r]. lin(b0,b1) inverted via the supertile base table.
__global__ __launch_bounds__(256) void kred(const float* __restrict__ part,
                                            const float* __restrict__ pospart,
                                            float* __restrict__ out) {
    const int T = blockIdx.x;
    const int r = threadIdx.x;

    auto linof = [](int a, int b) {   // a <= b, 0..31
        constexpr int base[4][4] = {{0, 36, 100, 164},
                                    {0, 228, 264, 328},
                                    {0, 0, 392, 428},
                                    {0, 0, 0, 492}};
        const int SI = a >> 3, SJ = b >> 3, x = a & 7, y = b & 7;
        int inner;
        if (SI == SJ) inner = (x << 3) - ((x * (x - 1)) >> 1) + (y - x);
        else          inner = (x << 3) + y;
        return base[SI][SJ] + inner;
    };

    float n = 0.0f;
    for (int bj = T; bj < 32; bj++)
        n += part[((size_t)linof(T, bj) << 9) + r];
    for (int bi = 0; bi < T; bi++)
        n += part[((size_t)linof(bi, T) << 9) + 256 + r];
    const float p = pospart[(T << 8) + r];

    float s = __logf(p + n + 1e-8f) - __logf(p);
    #pragma unroll
    for (int m = 1; m < 64; m <<= 1) s += __shfl_xor(s, m);
    __shared__ float red[4];
    if ((r & 63) == 0) red[r >> 6] = s;
    __syncthreads();
    if (r == 0)
        atomicAdd(out, (red[0] + red[1] + red[2] + red[3]) * (1.0f / (float)NROWS));
}

extern "C" void kernel_launch(void* const* d_in, const int* in_sizes, int n_in,
                              void* d_out, int out_size, void* d_ws, size_t ws_size,
                              hipStream_t stream) {
    (void)in_sizes; (void)n_in; (void)out_size; (void)ws_size;
    const float* emb = (const float*)d_in[0];
    unsigned short* En = (unsigned short*)d_ws;                          // 8 MB bf16
    float* pospart = (float*)((char*)d_ws + (size_t)NROWS * DIM * 2);    // 32 KB
    float* part    = pospart + 32 * 256;                                 // 1.05 MB

    hipMemsetAsync(d_out, 0, sizeof(float), stream);
    knorm<<<NROWS / 4, 256, 0, stream>>>(emb, En);
    kgemm<<<528, 1024, 0, stream>>>(En, part, pospart);
    kred<<<32, 256, 0, stream>>>(part, pospart, (float*)d_out);
}